// Round 2
// baseline (263.323 us; speedup 1.0000x reference)
//
#include <hip/hip_runtime.h>
#include <hip/hip_bf16.h>

#define NCOLS 16384
#define DDIM  256

typedef __attribute__((ext_vector_type(8))) short bf16x8;
typedef __attribute__((ext_vector_type(4))) float f32x4;
typedef __attribute__((ext_vector_type(4))) int   i32x4;

static __device__ __forceinline__ ushort f2bf_rne(float f) {
    unsigned u = __builtin_bit_cast(unsigned, f);
    unsigned r = (u + 0x7fffu + ((u >> 16) & 1u)) >> 16;
    return (ushort)r;
}

// ---- Kernel 1: column norms -> normalized transposed bf16 wnT[N][D]; zero S.
__global__ __launch_bounds__(256)
void k_normT(const float* __restrict__ W, ushort* __restrict__ wnT,
             float* __restrict__ S) {
    const int i = blockIdx.x * 256 + threadIdx.x;   // column index
    float s = 0.f;
    #pragma unroll 8
    for (int d = 0; d < DDIM; ++d) {
        float v = W[(size_t)d * NCOLS + i];
        s = fmaf(v, v, s);
    }
    const float rinv = 1.0f / fmaxf(sqrtf(s), 1e-8f);
    S[i] = 0.f;
    for (int d0 = 0; d0 < DDIM; d0 += 8) {
        union { ushort us[8]; i32x4 v4; } p;
        #pragma unroll
        for (int j = 0; j < 8; ++j) {
            float v = W[(size_t)(d0 + j) * NCOLS + i] * rinv;
            p.us[j] = f2bf_rne(v);
        }
        *reinterpret_cast<i32x4*>(&wnT[(size_t)i * DDIM + d0]) = p.v4;
    }
}

// ---- Kernel 2: fused Gram + exp + row-sum.
// Block: 256 threads (4 waves). BM=128 rows (32/wave). j-chunk = 2048 cols,
// staged in BN=64-col LDS tiles (padded stride). Grid = 128 * 8 = 1024.
#define BM 128
#define BN 64
#define JCHUNK 2048
#define NTILE (JCHUNK / BN)
#define LSTR 264   // bf16 elements per LDS row (256 + 8 pad -> 528B stride)

__global__ __launch_bounds__(256)
void k_gram(const ushort* __restrict__ wnT, float* __restrict__ S) {
    __shared__ ushort Bs[BN * LSTR];   // 33792 B
    const int tid  = threadIdx.x;
    const int lane = tid & 63;
    const int l15  = lane & 15;
    const int kof  = (lane >> 4) * 8;      // k element offset within 32-chunk
    const int wave = tid >> 6;
    const int ib   = blockIdx.x >> 3;      // 0..127  (i-tile)
    const int jc   = blockIdx.x & 7;       // 0..7    (j-chunk) == XCD id
    const int i0   = ib * BM + wave * 32;
    const int j0b  = jc * JCHUNK;

    // A fragments for this wave's 32 rows: 2 strips x 8 k-steps, 16B each.
    bf16x8 afrag[2][8];
    #pragma unroll
    for (int s = 0; s < 2; ++s)
        #pragma unroll
        for (int kk = 0; kk < 8; ++kk)
            afrag[s][kk] = *reinterpret_cast<const bf16x8*>(
                &wnT[(size_t)(i0 + s * 16 + l15) * DDIM + kk * 32 + kof]);

    float rowsum[2][4] = {{0.f,0.f,0.f,0.f},{0.f,0.f,0.f,0.f}};

    const int srow = tid >> 5;         // 0..7  (8 rows per staging pass)
    const int scol = (tid & 31) * 8;   // 32 lanes * 16B = one full 512B row

    for (int t = 0; t < NTILE; ++t) {
        const int j0 = j0b + t * BN;
        __syncthreads();               // previous tile fully consumed
        #pragma unroll
        for (int c = 0; c < 8; ++c) {
            const int r = c * 8 + srow;
            *reinterpret_cast<i32x4*>(&Bs[r * LSTR + scol]) =
                *reinterpret_cast<const i32x4*>(&wnT[(size_t)(j0 + r) * DDIM + scol]);
        }
        __syncthreads();
        #pragma unroll
        for (int jj = 0; jj < 4; ++jj) {
            bf16x8 b[8];
            #pragma unroll
            for (int kk = 0; kk < 8; ++kk)
                b[kk] = *reinterpret_cast<const bf16x8*>(
                    &Bs[(jj * 16 + l15) * LSTR + kk * 32 + kof]);
            #pragma unroll
            for (int s = 0; s < 2; ++s) {
                f32x4 acc = {0.f, 0.f, 0.f, 0.f};
                #pragma unroll
                for (int kk = 0; kk < 8; ++kk)
                    acc = __builtin_amdgcn_mfma_f32_16x16x32_bf16(
                        afrag[s][kk], b[kk], acc, 0, 0, 0);
                #pragma unroll
                for (int r = 0; r < 4; ++r)
                    rowsum[s][r] += exp2f((acc[r] - 1.0f) * 1.4426950408889634f);
            }
        }
    }

    // Reduce each row over the 16 lanes holding its 16 columns, then atomic.
    #pragma unroll
    for (int s = 0; s < 2; ++s)
        #pragma unroll
        for (int r = 0; r < 4; ++r) {
            float v = rowsum[s][r];
            v += __shfl_xor(v, 1, 64);
            v += __shfl_xor(v, 2, 64);
            v += __shfl_xor(v, 4, 64);
            v += __shfl_xor(v, 8, 64);
            if (l15 == 0)
                atomicAdd(&S[i0 + s * 16 + (lane >> 4) * 4 + r], v);
        }
}

// ---- Kernel 3: loss = lw * sum(log(S)) / N
__global__ __launch_bounds__(256)
void k_final(const float* __restrict__ S, const float* __restrict__ lw,
             float* __restrict__ out) {
    float a = 0.f;
    for (int i = threadIdx.x; i < NCOLS; i += 256) a += logf(S[i]);
    #pragma unroll
    for (int m = 1; m < 64; m <<= 1) a += __shfl_xor(a, m, 64);
    __shared__ float red[4];
    if ((threadIdx.x & 63) == 0) red[threadIdx.x >> 6] = a;
    __syncthreads();
    if (threadIdx.x == 0)
        out[0] = lw[0] * (red[0] + red[1] + red[2] + red[3]) / (float)NCOLS;
}

extern "C" void kernel_launch(void* const* d_in, const int* in_sizes, int n_in,
                              void* d_out, int out_size, void* d_ws, size_t ws_size,
                              hipStream_t stream) {
    const float* W  = (const float*)d_in[0];
    const float* lw = (const float*)d_in[1];
    float* out = (float*)d_out;

    ushort* wnT = (ushort*)d_ws;                                   // 8 MB
    float*  S   = (float*)((char*)d_ws + (size_t)NCOLS * DDIM * 2); // 64 KB

    k_normT<<<NCOLS / 256, 256, 0, stream>>>(W, wnT, S);
    k_gram <<<(NCOLS / BM) * (NCOLS / JCHUNK), 256, 0, stream>>>(wnT, S);
    k_final<<<1, 256, 0, stream>>>(S, lw, out);
}

// Round 4
// 244.378 us; speedup vs baseline: 1.0775x; 1.0775x over previous
//
#include <hip/hip_runtime.h>
#include <hip/hip_bf16.h>

#define NCOLS 16384
#define DDIM  256
#define TILE  256            // block tile: 256 rows x 256 cols
#define NT    (NCOLS / TILE) // 64 tiles per dim
#define BN    64             // cols per LDS sub-tile
#define SQRT_L2E 1.2011224087864498f  // sqrt(log2(e)); A*B picks up log2(e)

typedef __attribute__((ext_vector_type(8))) short bf16x8;
typedef __attribute__((ext_vector_type(4))) float f32x4;
typedef __attribute__((ext_vector_type(4))) int   i32x4;

typedef __attribute__((address_space(1))) const unsigned int gu32;
typedef __attribute__((address_space(3))) unsigned int       lu32;

static __device__ __forceinline__ ushort f2bf_rne(float f) {
    unsigned u = __builtin_bit_cast(unsigned, f);
    unsigned r = (u + 0x7fffu + ((u >> 16) & 1u)) >> 16;
    return (ushort)r;
}

// ---- Kernel 1: column norms -> wnT[i][d] = bf16( W[:,i]/max(||.||,eps) * sqrt(log2 e) )
// 256 blocks x 256 threads; block owns 64 columns, 4 d-stripes of 64.
__global__ __launch_bounds__(256)
void k_norm(const float* __restrict__ W, ushort* __restrict__ wnT,
            float* __restrict__ S) {
    __shared__ float red[4][64];
    __shared__ float scale_s[64];
    const int t  = threadIdx.x;
    const int il = t & 63, st = t >> 6;
    const int i  = blockIdx.x * 64 + il;
    float p = 0.f;
    #pragma unroll 8
    for (int j = 0; j < 64; ++j) {
        float v = W[(size_t)(st * 64 + j) * NCOLS + i];
        p = fmaf(v, v, p);
    }
    red[st][il] = p;
    __syncthreads();
    if (t < 64) {
        float n = sqrtf(red[0][t] + red[1][t] + red[2][t] + red[3][t]);
        scale_s[t] = SQRT_L2E / fmaxf(n, 1e-8f);
        S[blockIdx.x * 64 + t] = 0.f;           // zero row-sum accumulator
    }
    __syncthreads();
    const float sc = scale_s[il];
    #pragma unroll
    for (int j2 = 0; j2 < 8; ++j2) {
        union { ushort us[8]; i32x4 v; } pk;
        #pragma unroll
        for (int e = 0; e < 8; ++e) {
            float v = W[(size_t)(st * 64 + j2 * 8 + e) * NCOLS + i] * sc;
            pk.us[e] = f2bf_rne(v);
        }
        *reinterpret_cast<i32x4*>(&wnT[(size_t)i * DDIM + st * 64 + j2 * 8]) = pk.v;
    }
}

// ---- Kernel 2: symmetric fused Gram + exp + row/col sums.
// Grid 64x64 linear; block (ti,tj) with tj<ti exits. 4 waves x 64 rows (4 strips).
// B staged in double-buffered linear LDS via global_load_lds with XOR swizzle
// (rule #21: linear dest + inverse-swizzled SOURCE + swizzled READ).
__global__ __launch_bounds__(256, 2)
void k_gram(const ushort* __restrict__ wnT, float* __restrict__ S) {
    __shared__ ushort Bs[2][BN * DDIM];     // 2 x 32 KiB, 512 B per col-row
    const int bx = blockIdx.x;
    const int ti = bx & 63, tj = bx >> 6;
    if (tj < ti) return;                    // lower triangle: dead
    const bool diag = (ti == tj);
    const int i0 = ti * TILE, j0 = tj * TILE;

    const int tid  = threadIdx.x;
    const int lane = tid & 63, wave = tid >> 6;
    const int l15  = lane & 15;
    const int kq16 = ((lane >> 4) & 3) * 16;      // k-subgroup byte offset
    const int xorm = (lane & 7) << 4;             // read-side swizzle (row&7)<<4

    // A fragments: 4 strips x 8 k-steps (rows i0 + wave*64 + s*16 + l15)
    bf16x8 afrag[4][8];
    #pragma unroll
    for (int s = 0; s < 4; ++s) {
        const ushort* arow = wnT + (size_t)(i0 + wave * 64 + s * 16 + l15) * DDIM;
        #pragma unroll
        for (int kk = 0; kk < 8; ++kk)
            afrag[s][kk] = *reinterpret_cast<const bf16x8*>(
                arow + kk * 32 + (kq16 >> 1));
    }

    // stage sub-tile jt into Bs[b]: 8 insts/wave, 2 cols (512B each) per inst.
    auto stage = [&](int b, int jt) {
        #pragma unroll
        for (int q = 0; q < 8; ++q) {
            const int r0  = wave * 16 + q * 2;
            const int row = r0 + (lane >> 5);               // local col 0..63
            const int sb  = ((lane & 31) * 16) ^ ((row & 7) << 4);
            const ushort* g = wnT + (size_t)(j0 + jt * BN + row) * DDIM + (sb >> 1);
            char* l = (char*)&Bs[b][0] + (r0 << 9);          // wave-uniform
            __builtin_amdgcn_global_load_lds((gu32*)g, (lu32*)l, 16, 0, 0);
        }
    };

    float rowsum[4][4];
    #pragma unroll
    for (int s = 0; s < 4; ++s)
        #pragma unroll
        for (int r = 0; r < 4; ++r) rowsum[s][r] = 0.f;

    stage(0, 0);
    __syncthreads();                       // drains vmcnt before barrier

    int cur = 0;
    for (int jt = 0; jt < 4; ++jt) {
        if (jt < 3) stage(cur ^ 1, jt + 1);     // prefetch overlaps compute
        float colacc[4] = {0.f, 0.f, 0.f, 0.f};
        const char* bufbase = (const char*)&Bs[cur][0];
        #pragma unroll
        for (int jj = 0; jj < 4; ++jj) {
            const char* brow = bufbase + ((jj * 16 + l15) << 9);
            bf16x8 b[8];
            #pragma unroll
            for (int kk = 0; kk < 8; ++kk)
                b[kk] = *reinterpret_cast<const bf16x8*>(
                    brow + (((kk * 64 + kq16) ^ xorm)));
            #pragma unroll
            for (int s = 0; s < 4; ++s) {
                f32x4 acc = {0.f, 0.f, 0.f, 0.f};
                #pragma unroll
                for (int kk = 0; kk < 8; ++kk)
                    acc = __builtin_amdgcn_mfma_f32_16x16x32_bf16(
                        afrag[s][kk], b[kk], acc, 0, 0, 0);
                #pragma unroll
                for (int r = 0; r < 4; ++r) {
                    float e = __builtin_amdgcn_exp2f(acc[r]);  // = exp(G)
                    rowsum[s][r] += e;
                    colacc[jj]   += e;
                }
            }
        }
        if (!diag) {   // mirrored contribution: S[j] += sum_i exp(G[i,j])
            #pragma unroll
            for (int jj = 0; jj < 4; ++jj) {
                float v = colacc[jj];
                v += __shfl_xor(v, 16, 64);
                v += __shfl_xor(v, 32, 64);
                if (lane < 16)
                    atomicAdd(&S[j0 + jt * BN + jj * 16 + lane], v);
            }
        }
        __syncthreads();                   // staging done + all reads of cur done
        cur ^= 1;
    }

    // row sums: reduce 16 col-lanes, C layout col=lane&15 row=(lane>>4)*4+r
    #pragma unroll
    for (int s = 0; s < 4; ++s)
        #pragma unroll
        for (int r = 0; r < 4; ++r) {
            float v = rowsum[s][r];
            v += __shfl_xor(v, 1, 64);
            v += __shfl_xor(v, 2, 64);
            v += __shfl_xor(v, 4, 64);
            v += __shfl_xor(v, 8, 64);
            if (l15 == 0)
                atomicAdd(&S[i0 + wave * 64 + s * 16 + (lane >> 4) * 4 + r], v);
        }
}

// ---- Kernel 3: loss = lw * (ln2 * sum(log2(S)) - N) / N   (the -1 folded here)
__global__ __launch_bounds__(1024)
void k_final(const float* __restrict__ S, const float* __restrict__ lw,
             float* __restrict__ out) {
    float a = 0.f;
    for (int i = threadIdx.x; i < NCOLS; i += 1024)
        a += __builtin_amdgcn_logf(S[i]);          // log2
    #pragma unroll
    for (int m = 1; m < 64; m <<= 1) a += __shfl_xor(a, m, 64);
    __shared__ float red[16];
    if ((threadIdx.x & 63) == 0) red[threadIdx.x >> 6] = a;
    __syncthreads();
    if (threadIdx.x == 0) {
        float tot = 0.f;
        #pragma unroll
        for (int k = 0; k < 16; ++k) tot += red[k];
        out[0] = lw[0] * (tot * 0.6931471805599453f - (float)NCOLS) / (float)NCOLS;
    }
}

extern "C" void kernel_launch(void* const* d_in, const int* in_sizes, int n_in,
                              void* d_out, int out_size, void* d_ws, size_t ws_size,
                              hipStream_t stream) {
    const float* W  = (const float*)d_in[0];
    const float* lw = (const float*)d_in[1];
    float* out = (float*)d_out;

    ushort* wnT = (ushort*)d_ws;                                    // 8 MiB
    float*  S   = (float*)((char*)d_ws + (size_t)NCOLS * DDIM * 2); // 64 KiB

    k_norm <<<NCOLS / 64, 256, 0, stream>>>(W, wnT, S);
    k_gram <<<NT * NT, 256, 0, stream>>>(wnT, S);
    k_final<<<1, 1024, 0, stream>>>(S, lw, out);
}

// Round 5
// 211.508 us; speedup vs baseline: 1.2450x; 1.1554x over previous
//
#include <hip/hip_runtime.h>
#include <hip/hip_bf16.h>

#define NCOLS 16384
#define DDIM  256
#define TILE  256            // block tile: 256 rows x 256 cols
#define NTI   64             // tiles per dim
#define NBLK  2080           // NTI*(NTI+1)/2 upper-triangle blocks
#define BN    32             // cols per LDS sub-tile (double-buffered)
#define SQRT_L2E 1.2011224087864498f  // sqrt(log2 e); A*B picks up log2(e)

typedef __attribute__((ext_vector_type(8))) short bf16x8;
typedef __attribute__((ext_vector_type(4))) float f32x4;
typedef __attribute__((ext_vector_type(4))) int   i32x4;

typedef __attribute__((address_space(1))) const unsigned int gu32;
typedef __attribute__((address_space(3))) unsigned int       lu32;

static __device__ __forceinline__ ushort f2bf_rne(float f) {
    unsigned u = __builtin_bit_cast(unsigned, f);
    unsigned r = (u + 0x7fffu + ((u >> 16) & 1u)) >> 16;
    return (ushort)r;
}

// ---- Kernel 1: single-pass column norm + scale + bf16 pack (transposed out).
// 512 blocks x 256 thr; block owns 32 cols; thread caches 32 W values in regs.
__global__ __launch_bounds__(256)
void k_norm(const float* __restrict__ W, ushort* __restrict__ wnT,
            float* __restrict__ S) {
    __shared__ float red[8][32];
    __shared__ float scale_s[32];
    const int tid = threadIdx.x;
    const int il = tid & 31, st = tid >> 5;
    const int col = blockIdx.x * 32 + il;
    float v[32];
    float p = 0.f;
    #pragma unroll
    for (int e = 0; e < 32; ++e) {
        v[e] = W[(size_t)(st * 32 + e) * NCOLS + col];
        p = fmaf(v[e], v[e], p);
    }
    red[st][il] = p;
    __syncthreads();
    if (tid < 32) {
        float n = 0.f;
        #pragma unroll
        for (int q = 0; q < 8; ++q) n += red[q][tid];
        scale_s[tid] = SQRT_L2E / fmaxf(sqrtf(n), 1e-8f);
        S[blockIdx.x * 32 + tid] = 0.f;          // zero row-sum accumulator
    }
    __syncthreads();
    const float sc = scale_s[il];
    #pragma unroll
    for (int g = 0; g < 4; ++g) {
        union { ushort us[8]; i32x4 w4; } pk;
        #pragma unroll
        for (int e2 = 0; e2 < 8; ++e2) pk.us[e2] = f2bf_rne(v[g * 8 + e2] * sc);
        *reinterpret_cast<i32x4*>(&wnT[(size_t)col * DDIM + st * 32 + g * 8]) = pk.w4;
    }
}

// ---- Kernel 2: symmetric fused Gram + exp + row/col sums.
// Grid = exactly NBLK upper-triangle tiles. 4 waves x 64 rows (afrag resident).
// B double-buffered in 2x16 KiB LDS via global_load_lds; XOR swizzle applied
// on the global SOURCE and the LDS READ (rule #21), dest linear.
// All atomics deferred to kernel end; col partials live in registers.
__global__ __launch_bounds__(256)
void k_gram(const ushort* __restrict__ wnT, float* __restrict__ S) {
    __shared__ ushort Bs[2][BN * DDIM];          // 2 x 16 KiB

    // decode upper-triangle (ti,tj), row-major: (0,0),(0,1)..(0,63),(1,1)..
    const int t = blockIdx.x;
    const int u = (NBLK - 1) - t;
    int k = (int)((sqrtf((float)(8 * u + 1)) - 1.0f) * 0.5f);
    while ((k + 1) * (k + 2) / 2 <= u) ++k;
    while (k * (k + 1) / 2 > u) --k;
    const int ti = 63 - k;
    const int tj = 63 - (u - k * (k + 1) / 2);
    const bool diag = (ti == tj);
    const int i0 = ti * TILE, j0 = tj * TILE;

    const int tid  = threadIdx.x;
    const int lane = tid & 63, wave = tid >> 6;
    const int l15  = lane & 15;
    const int kq16 = ((lane >> 4) & 3) * 16;     // k-subgroup byte offset
    const int xorm = (lane & 7) << 4;            // read-side swizzle

    // A fragments: 4 strips x 8 k-steps, rows i0 + wave*64 + s*16 + l15
    bf16x8 afrag[4][8];
    #pragma unroll
    for (int s = 0; s < 4; ++s) {
        const ushort* arow = wnT + (size_t)(i0 + wave * 64 + s * 16 + l15) * DDIM;
        #pragma unroll
        for (int kk = 0; kk < 8; ++kk)
            afrag[s][kk] = *reinterpret_cast<const bf16x8*>(
                arow + kk * 32 + (kq16 >> 1));
    }

    auto stage = [&](int b, int jt2) {
        #pragma unroll
        for (int q = 0; q < 4; ++q) {
            const int r0  = wave * 8 + q * 2;
            const int row = r0 + (lane >> 5);
            const int sb  = ((lane & 31) * 16) ^ ((row & 7) << 4);
            const ushort* g = wnT + (size_t)(j0 + jt2 * BN + row) * DDIM + (sb >> 1);
            char* l = (char*)&Bs[b][0] + (r0 << 9);   // wave-uniform dest
            __builtin_amdgcn_global_load_lds((gu32*)g, (lu32*)l, 16, 0, 0);
        }
    };

    float rowsum[4][4];
    float colacc[16];
    #pragma unroll
    for (int s = 0; s < 4; ++s)
        #pragma unroll
        for (int r = 0; r < 4; ++r) rowsum[s][r] = 0.f;
    #pragma unroll
    for (int c = 0; c < 16; ++c) colacc[c] = 0.f;

    stage(0, 0);
    __syncthreads();

    #pragma unroll
    for (int jt = 0; jt < 8; ++jt) {
        if (jt < 7) stage((jt + 1) & 1, jt + 1);      // prefetch overlaps compute
        const char* bufbase = (const char*)&Bs[jt & 1][0];
        #pragma unroll
        for (int jj = 0; jj < 2; ++jj) {
            const char* brow = bufbase + ((jj * 16 + l15) << 9);
            bf16x8 b[8];
            #pragma unroll
            for (int kk = 0; kk < 8; ++kk)
                b[kk] = *reinterpret_cast<const bf16x8*>(
                    brow + ((kk * 64 + kq16) ^ xorm));
            #pragma unroll
            for (int s = 0; s < 4; ++s) {
                f32x4 acc = {0.f, 0.f, 0.f, 0.f};
                #pragma unroll
                for (int kk = 0; kk < 8; ++kk)
                    acc = __builtin_amdgcn_mfma_f32_16x16x32_bf16(
                        afrag[s][kk], b[kk], acc, 0, 0, 0);
                #pragma unroll
                for (int r = 0; r < 4; ++r) {
                    float e = __builtin_amdgcn_exp2f(acc[r]);   // = exp(G)
                    rowsum[s][r]        += e;
                    colacc[jt * 2 + jj] += e;
                }
            }
        }
        __syncthreads();           // drains prefetch vmcnt + all reads of cur buf
    }

    // --- row sums: reduce 16 col-lanes; C layout col=lane&15, row=(lane>>4)*4+r
    #pragma unroll
    for (int s = 0; s < 4; ++s)
        #pragma unroll
        for (int r = 0; r < 4; ++r) {
            float v = rowsum[s][r];
            v += __shfl_xor(v, 1, 64);
            v += __shfl_xor(v, 2, 64);
            v += __shfl_xor(v, 4, 64);
            v += __shfl_xor(v, 8, 64);
            if (l15 == 0)
                atomicAdd(&S[i0 + wave * 64 + s * 16 + (lane >> 4) * 4 + r], v);
        }

    // --- mirrored col sums (off-diag only): wave-reduce, LDS cross-wave, 1 atomic/col
    if (!diag) {
        float* R = (float*)&Bs[0][0];              // reuse LDS (4 KiB)
        #pragma unroll
        for (int c = 0; c < 16; ++c) {
            float v = colacc[c];
            v += __shfl_xor(v, 16, 64);
            v += __shfl_xor(v, 32, 64);
            if (lane < 16) R[wave * 256 + c * 16 + lane] = v;
        }
        __syncthreads();
        const float sum = R[tid] + R[256 + tid] + R[512 + tid] + R[768 + tid];
        atomicAdd(&S[j0 + tid], sum);
    }
}

// ---- Kernel 3: loss = lw * (ln2 * sum(log2 S) - N) / N   (the -1 folded here)
__global__ __launch_bounds__(1024)
void k_final(const float* __restrict__ S, const float* __restrict__ lw,
             float* __restrict__ out) {
    float a = 0.f;
    for (int i = threadIdx.x; i < NCOLS; i += 1024)
        a += __builtin_amdgcn_logf(S[i]);          // log2
    #pragma unroll
    for (int m = 1; m < 64; m <<= 1) a += __shfl_xor(a, m, 64);
    __shared__ float red[16];
    if ((threadIdx.x & 63) == 0) red[threadIdx.x >> 6] = a;
    __syncthreads();
    if (threadIdx.x == 0) {
        float tot = 0.f;
        #pragma unroll
        for (int q = 0; q < 16; ++q) tot += red[q];
        out[0] = lw[0] * (tot * 0.6931471805599453f - (float)NCOLS) / (float)NCOLS;
    }
}

extern "C" void kernel_launch(void* const* d_in, const int* in_sizes, int n_in,
                              void* d_out, int out_size, void* d_ws, size_t ws_size,
                              hipStream_t stream) {
    const float* W  = (const float*)d_in[0];
    const float* lw = (const float*)d_in[1];
    float* out = (float*)d_out;

    ushort* wnT = (ushort*)d_ws;                                    // 8 MiB
    float*  S   = (float*)((char*)d_ws + (size_t)NCOLS * DDIM * 2); // 64 KiB

    k_norm <<<NCOLS / 32, 256, 0, stream>>>(W, wnT, S);
    k_gram <<<NBLK, 256, 0, stream>>>(wnT, S);
    k_final<<<1, 1024, 0, stream>>>(S, lw, out);
}